// Round 6
// baseline (278.504 us; speedup 1.0000x reference)
//
#include <hip/hip_runtime.h>
#include <stdint.h>

typedef uint16_t u16;
typedef uint32_t u32;
typedef __attribute__((ext_vector_type(4))) float f32x4;
typedef __attribute__((ext_vector_type(4))) unsigned short us4;

#define NB   16
#define NN   512
#define FF   625      // H*W (= F)
#define FH   937      // int(625*1.5)
#define ROWS 8192     // NB*NN
#define F4   160      // 640/4 f32x4 slots per padded X row
#define GQ   4        // att-adjacent rows per build_L block
#define KX   640      // padded F   (K of G1 / cols of Xb / N-stride of G2a,G2bt)
#define KH   960      // padded Fh  (K of G2 / cols of h / N-stride of G1a,G1bt)
#define N1   1874     // G1 real N (2*937)
#define N2   1250     // G2 real N (2*625)

using frag_ab = __attribute__((ext_vector_type(8))) short;  // 8 bf16
using frag_cd = __attribute__((ext_vector_type(4))) float;  // 4 fp32

__device__ __forceinline__ u16 f32_bf16(float f) {
  union { float f; uint32_t u; } x; x.f = f;
  uint32_t r = x.u + 0x7fffu + ((x.u >> 16) & 1u);   // RNE
  return (u16)(r >> 16);
}
__device__ __forceinline__ void gload_lds16(const void* g, void* l) {
  __builtin_amdgcn_global_load_lds((__attribute__((address_space(1))) void*)g,
                                   (__attribute__((address_space(3))) void*)l,
                                   16, 0, 0);
}

// ---------------------------------------------------------------------------
// prep (R12): no more Xt (re-association removed L·X). Weight transposes now
// split on N (output-col concat), not K.
//  [0,16)        att rank-sort per batch -> order[b][512], att_s[b][512]
//  [16,4112)     pad_x: x4 -> Xpad f32x4 + Xb bf16 [8192][640]; XCD-aligned
//  [4112,5312)   W1 -> W1ct [1920][640] B^T  (row n: col of [W1a|W1b])
//  [5312,6512)   W2 -> W2ct [1280][960] B^T
// ---------------------------------------------------------------------------
__global__ __launch_bounds__(256) void prep(
    const float* __restrict__ x4, const float* __restrict__ att,
    const float* __restrict__ W1, const float* __restrict__ W2,
    f32x4* __restrict__ Xpad, u16* __restrict__ Xb,
    u16* __restrict__ W1ct, u16* __restrict__ W2ct,
    u16* __restrict__ order, float* __restrict__ att_s)
{
  __shared__ __align__(16) float smem[1056];   // unioned: sort 512 / tile 32x33
  const int blk = blockIdx.x;
  const int tid = threadIdx.x;

  if (blk < 16) {
    // att rank-sort: rank = #{j: a_j < a_i || (== && j<i)}
    float* a_sh = smem;
    const int b = blk;
    a_sh[tid]       = att[b * NN + tid];
    a_sh[tid + 256] = att[b * NN + tid + 256];
    __syncthreads();
    #pragma unroll
    for (int h = 0; h < 2; ++h) {
      const int i = tid + h * 256;
      const float ai = a_sh[i];
      int r = 0;
      for (int j = 0; j < NN; ++j) {
        const float aj = a_sh[j];
        r += (aj < ai) || (aj == ai && j < i);
      }
      order[(size_t)b * NN + r] = (u16)i;
      att_s[(size_t)b * NN + r] = ai;
    }
  } else if (blk < 4112) {
    const int idx = blk - 16;
    const int xcd = idx & 7, loc = idx >> 3;    // loc 0..511
    const int row0 = xcd * 1024 + loc * 2;
    for (int s = tid; s < 320; s += 256) {
      const int row = row0 + (s >= 160);
      const int k4 = (s >= 160) ? s - 160 : s;
      f32x4 v; us4 o;
      #pragma unroll
      for (int t = 0; t < 4; ++t) {
        const int f = k4 * 4 + t;
        float x = (f < FF) ? x4[(size_t)row * FF + f] : 0.f;
        v[t] = x; o[t] = f32_bf16(x);
      }
      Xpad[(size_t)row * F4 + k4] = v;
      *(us4*)(Xb + (size_t)row * KX + k4 * 4) = o;
    }
  } else if (blk < 5312) {
    float (*tile)[33] = (float(*)[33])smem;
    const int bb = blk - 4112;                  // 20 kt x 60 nt
    const int kt = bb % 20, ntl = bb / 20;
    const int tx = tid & 31, ty = tid >> 5;
    #pragma unroll
    for (int r = 0; r < 4; ++r) {
      const int k = kt * 32 + ty + r * 8;       // 0..639 (F index)
      const int n = ntl * 32 + tx;              // 0..1919 (col of [W1a|W1b])
      float v = 0.f;
      int c = -1, np = 0;
      if (n < 937) { c = 0; np = n; }
      else if (n < 1874) { c = 1; np = n - 937; }
      if (c >= 0 && k < 625) v = W1[((size_t)c * 625 + k) * FH + np];
      tile[ty + r * 8][tx] = v;
    }
    __syncthreads();
    #pragma unroll
    for (int r = 0; r < 4; ++r) {
      const int n = ntl * 32 + ty + r * 8;
      const int k = kt * 32 + tx;
      W1ct[(size_t)n * KX + k] = f32_bf16(tile[tx][ty + r * 8]);
    }
  } else {
    float (*tile)[33] = (float(*)[33])smem;
    const int bb = blk - 5312;                  // 30 kt x 40 nt
    const int kt = bb % 30, ntl = bb / 30;
    const int tx = tid & 31, ty = tid >> 5;
    #pragma unroll
    for (int r = 0; r < 4; ++r) {
      const int k = kt * 32 + ty + r * 8;       // 0..959 (Fh index)
      const int n = ntl * 32 + tx;              // 0..1279 (col of [W2a|W2b])
      float v = 0.f;
      int c = -1, np = 0;
      if (n < 625) { c = 0; np = n; }
      else if (n < 1250) { c = 1; np = n - 625; }
      if (c >= 0 && k < 937) v = W2[((size_t)c * 937 + k) * FF + np];
      tile[ty + r * 8][tx] = v;
    }
    __syncthreads();
    #pragma unroll
    for (int r = 0; r < 4; ++r) {
      const int n = ntl * 32 + ty + r * 8;
      const int k = kt * 32 + tx;
      W2ct[(size_t)n * KH + k] = f32_bf16(tile[tx][ty + r * 8]);
    }
  }
}

// ---------------------------------------------------------------------------
// gemm_core (R12): compute core unchanged (R5/R6-proven XOR chunk swizzle).
// LDS passed in by caller (unioned in fused kernel). Two epilogue modes:
//  MODE 0 (G-split): cols < NA -> f32 normal store into C (ldc); cols in
//    [NA,NSTO) -> bf16 TRANSPOSED per batch into Ct[(b*NPB + col-NA)*512+node]
//    (R11-proven WT path). No bias/relu.
//  MODE 1 (S): v = col<NR ? relu(acc + Cadd[row*lda+col] + bias[col]) : 0,
//    stored for col < NSTO (bf16 or f32).
// ---------------------------------------------------------------------------
template <int KS, int NTILE, int MODE, int NA, int NR, int NSTO, int NPB, bool OBF16>
__device__ __forceinline__ void gemm_core(
    const u16* __restrict__ At,      // A tile base: rows 0..127, stride KS
    const u16* __restrict__ Btt,     // B^T tile base: rows 0..NTILE-1, stride KS
    const float* __restrict__ bias, const float* __restrict__ Cadd, int lda,
    void* __restrict__ C, u16* __restrict__ Ct,
    long crow0, int col0, int ldc,
    u16* Ash, u16* Bsh)
{
  constexpr int NI = NTILE / 32;
  constexpr int BR = NTILE / 32;

  const int tid  = threadIdx.x;
  const int lane = tid & 63;
  const int wave = tid >> 6;
  const int wm = wave & 1, wn = wave >> 1;
  const int q = lane >> 4, l16 = lane & 15;

  const u16* pa[4]; const u16* pb[BR];
  #pragma unroll
  for (int r = 0; r < 4; ++r) {
    const int ci = r * 256 + tid;
    const int row = ci >> 3, cpos = ci & 7;
    pa[r] = At + (size_t)row * KS + (cpos ^ (row & 7)) * 8;
  }
  #pragma unroll
  for (int r = 0; r < BR; ++r) {
    const int ci = r * 256 + tid;
    const int row = ci >> 3, cpos = ci & 7;
    pb[r] = Btt + (size_t)row * KS + (cpos ^ (row & 7)) * 8;
  }
  const int wbase = (tid & 192) * 8;

  const frag_ab* fA[4][2]; const frag_ab* fB[NI][2];
  #pragma unroll
  for (int mi = 0; mi < 4; ++mi) {
    const int row = wm * 64 + mi * 16 + l16;
    fA[mi][0] = (const frag_ab*)&Ash[row * 64 + ((q    ) ^ (l16 & 7)) * 8];
    fA[mi][1] = (const frag_ab*)&Ash[row * 64 + ((q + 4) ^ (l16 & 7)) * 8];
  }
  #pragma unroll
  for (int ni = 0; ni < NI; ++ni) {
    const int row = wn * (NTILE / 2) + ni * 16 + l16;
    fB[ni][0] = (const frag_ab*)&Bsh[row * 64 + ((q    ) ^ (l16 & 7)) * 8];
    fB[ni][1] = (const frag_ab*)&Bsh[row * 64 + ((q + 4) ^ (l16 & 7)) * 8];
  }

  frag_cd acc[4][NI] = {};

  constexpr int KT = KS / 64;
  for (int kt = 0; kt < KT; ++kt) {
    __syncthreads();
    #pragma unroll
    for (int r = 0; r < 4; ++r) { gload_lds16(pa[r], &Ash[r * 2048 + wbase]); pa[r] += 64; }
    #pragma unroll
    for (int r = 0; r < BR; ++r) { gload_lds16(pb[r], &Bsh[r * 2048 + wbase]); pb[r] += 64; }
    __syncthreads();

    #pragma unroll
    for (int kk = 0; kk < 2; ++kk) {
      frag_ab av[4], bv[NI];
      #pragma unroll
      for (int mi = 0; mi < 4; ++mi) av[mi] = *fA[mi][kk];
      #pragma unroll
      for (int ni = 0; ni < NI; ++ni) bv[ni] = *fB[ni][kk];
      #pragma unroll
      for (int mi = 0; mi < 4; ++mi)
        #pragma unroll
        for (int ni = 0; ni < NI; ++ni)
          acc[mi][ni] = __builtin_amdgcn_mfma_f32_16x16x32_bf16(
              av[mi], bv[ni], acc[mi][ni], 0, 0, 0);
    }
  }

  #pragma unroll
  for (int ni = 0; ni < NI; ++ni) {
    const int col = col0 + wn * (NTILE / 2) + ni * 16 + l16;
    if (col >= NSTO) continue;
    if (MODE == 0) {
      const bool wt = (col >= NA);
      #pragma unroll
      for (int mi = 0; mi < 4; ++mi) {
        us4 tv;
        #pragma unroll
        for (int r = 0; r < 4; ++r) {
          const long rowg = crow0 + wm * 64 + mi * 16 + q * 4 + r;
          const float v = acc[mi][ni][r];
          if (wt) tv[r] = f32_bf16(v);
          else    ((float*)C)[rowg * (size_t)ldc + col] = v;
        }
        if (wt) {
          const long bb = crow0 >> 9;
          const int node = (int)(crow0 & 511) + wm * 64 + mi * 16 + q * 4;
          *(us4*)(Ct + ((size_t)bb * NPB + (col - NA)) * 512 + node) = tv;
        }
      }
    } else {
      const bool ok = (col < NR);
      const float bv = ok ? bias[col] : 0.f;
      #pragma unroll
      for (int mi = 0; mi < 4; ++mi) {
        #pragma unroll
        for (int r = 0; r < 4; ++r) {
          const long rowg = crow0 + wm * 64 + mi * 16 + q * 4 + r;
          float v = 0.f;
          if (ok) v = fmaxf(acc[mi][ni][r] + Cadd[rowg * (size_t)lda + col] + bv, 0.f);
          if (OBF16) ((u16*)C)[rowg * (size_t)ldc + col] = f32_bf16(v);
          else       ((float*)C)[rowg * (size_t)ldc + col] = v;
        }
      }
    }
  }
}

// ---------------------------------------------------------------------------
// build_L body (R9-proven, LDS carved from caller buffer).
// ---------------------------------------------------------------------------
__device__ __forceinline__ void build_L_body(
    u16* smem, const int blk, const int tid,
    const f32x4* __restrict__ Xpad, const u16* __restrict__ order,
    const float* __restrict__ att_s, u16* __restrict__ L)
{
  float* atts = (float*)smem;                 // [512]   u16 off [0,1024)
  u16*  ords  = smem + 1024;                  // [512]   [1024,1536)
  u16*  cand  = smem + 1536;                  // [512]   [1536,2048)
  u16*  flag  = smem + 2048;                  // [GQ*512][2048,4096)
  int*  ncand = (int*)(smem + 4096);
  int*  naccs = (int*)(smem + 4098);          // [GQ]

  const int xcd = blk & 7, sub = blk >> 3;    // sub 0..255
  const int b = xcd * 2 + (sub >> 7);
  const int p0 = (sub & 127) * GQ;
  const f32x4* Xb4 = Xpad + (size_t)b * NN * F4;

  atts[tid]       = att_s[b * NN + tid];
  atts[tid + 256] = att_s[b * NN + tid + 256];
  ords[tid]       = order[b * NN + tid];
  ords[tid + 256] = order[b * NN + tid + 256];
  {
    u32* fz = (u32*)flag;                     // GQ*512 u16 = 1024 u32
    #pragma unroll
    for (int s = 0; s < GQ; ++s) fz[tid + s * 256] = 0;
  }
  if (tid == 0) *ncand = 0;
  if (tid < GQ) naccs[tid] = 0;
  __syncthreads();

  float av[GQ]; int ig[GQ];
  #pragma unroll
  for (int g = 0; g < GQ; ++g) { av[g] = atts[p0 + g]; ig[g] = ords[p0 + g]; }
  if (tid < GQ) flag[tid * 512 + ords[p0 + tid]] = 1;   // self (A+I diagonal)

  {
    const float lo = av[0] - 0.0501f, hi = av[GQ - 1] + 0.0501f;
    const bool q0 = (atts[tid] >= lo) && (atts[tid] <= hi);
    const bool q1 = (atts[tid + 256] >= lo) && (atts[tid + 256] <= hi);
    const unsigned long long m0 = __ballot(q0);
    const unsigned long long m1 = __ballot(q1);
    const int c0 = __popcll(m0);
    const int c1 = __popcll(m1);
    const int lane = tid & 63;
    int base = 0;
    if (lane == 0 && (c0 + c1)) base = atomicAdd(ncand, c0 + c1);
    base = __shfl(base, 0, 64);
    const unsigned long long below = (1ull << lane) - 1ull;
    if (q0) cand[base + __popcll(m0 & below)] = (u16)tid;
    if (q1) cand[base + c0 + __popcll(m1 & below)] = (u16)(tid + 256);
  }
  __syncthreads();
  const int nc = *ncand;

  const int hl = tid & 31;
  const int hw = tid >> 5;

  f32x4 xi[GQ][5];
  #pragma unroll
  for (int g = 0; g < GQ; ++g) {
    const f32x4* Xi = Xb4 + (size_t)ig[g] * F4;
    #pragma unroll
    for (int s = 0; s < 5; ++s) xi[g][s] = Xi[s * 32 + hl];
  }

  for (int c = hw; c < nc; c += 8) {
    const int p = cand[c];
    const int j = ords[p];
    const float aj = atts[p];
    const f32x4* Xj = Xb4 + (size_t)j * F4;
    f32x4 xj[5];
    #pragma unroll
    for (int s = 0; s < 5; ++s) xj[s] = Xj[s * 32 + hl];

    float pd[GQ];
    #pragma unroll
    for (int g = 0; g < GQ; ++g) {
      float p2 = 0.f;   // EXACT summation order of the original per-row kernel
      #pragma unroll
      for (int t = 0; t < 4; ++t) {
        p2 += fabsf(xi[g][0][t] - xj[0][t]) + fabsf(xi[g][1][t] - xj[1][t])
            + fabsf(xi[g][2][t] - xj[2][t]) + fabsf(xi[g][3][t] - xj[3][t])
            + fabsf(xi[g][4][t] - xj[4][t]);
      }
      pd[g] = p2;
    }
    #pragma unroll
    for (int off = 16; off; off >>= 1) {
      #pragma unroll
      for (int g = 0; g < GQ; ++g) pd[g] += __shfl_xor(pd[g], off, 64);
    }
    if (hl == 0) {
      #pragma unroll
      for (int g = 0; g < GQ; ++g) {
        if (pd[g] <= 180.0f && fabsf(av[g] - aj) <= 0.05f && j != ig[g]) {
          flag[g * 512 + j] = 1;
          atomicAdd(&naccs[g], 1);
        }
      }
    }
  }
  __syncthreads();

  #pragma unroll
  for (int g = 0; g < GQ; ++g) {
    const u16 dv = f32_bf16(1.0f / (float)(naccs[g] + 1));
    const long row = (long)b * NN + ig[g];
    const u32 lo2 = flag[g * 512 + 2 * tid]     ? (u32)dv : 0u;
    const u32 hi2 = flag[g * 512 + 2 * tid + 1] ? (u32)dv : 0u;
    *(u32*)(L + (size_t)row * 512 + 2 * tid) = lo2 | (hi2 << 16);
  }
}

// ---------------------------------------------------------------------------
// g1_bl (R12): build_L and G1 = Xb·[W1a|W1b] fused in ONE launch — they are
// independent (both need only prep) and use complementary pipes (VALU/L2 vs
// MFMA). Interleaved in 376-block chunks (120 G1 + 256 BL, 8-aligned so both
// sides' XCD data-locality mappings survive). 3008 = 8*376 blocks total.
// G1 epilogue: cols<937 -> G1a f32; cols 937..1873 -> G1bt bf16 transposed.
// ---------------------------------------------------------------------------
__global__ __launch_bounds__(256) void g1_bl(
    const u16* __restrict__ Xb, const u16* __restrict__ W1ct,
    float* __restrict__ G1a, u16* __restrict__ G1bt,
    const f32x4* __restrict__ Xpad, const u16* __restrict__ order,
    const float* __restrict__ att_s, u16* __restrict__ L)
{
  __shared__ __align__(16) u16 smem[16384];     // 32 KB unioned
  const int blk0 = blockIdx.x;
  const int g = blk0 / 376, r = blk0 % 376;
  if (r < 120) {
    const int idx = g * 120 + r;                // 0..959
    const int y = idx / 64, x = idx % 64;
    const int mt = ((x & 7) << 3) | (x >> 3);   // XCD-aligned m-tile
    gemm_core<KX, 128, 0, FH, N1, N1, KH, false>(
        Xb + (size_t)mt * 128 * KX, W1ct + (size_t)y * 128 * KX,
        nullptr, nullptr, 0, (void*)G1a, G1bt,
        (long)mt * 128, y * 128, KH, smem, smem + 8192);
  } else {
    build_L_body(smem, g * 256 + (r - 120), threadIdx.x, Xpad, order, att_s, L);
  }
}

// G2 = h·[W2a|W2b]: cols<625 -> G2a f32; cols 625..1249 -> G2bt bf16 transposed.
__global__ __launch_bounds__(256) void g2(
    const u16* __restrict__ h, const u16* __restrict__ W2ct,
    float* __restrict__ G2a, u16* __restrict__ G2bt)
{
  __shared__ __align__(16) u16 smem[16384];
  const int x = blockIdx.x;
  const int mt = ((x & 7) << 3) | (x >> 3);
  gemm_core<KH, 128, 0, FF, N2, N2, KX, false>(
      h + (size_t)mt * 128 * KH, W2ct + (size_t)blockIdx.y * 128 * KH,
      nullptr, nullptr, 0, (void*)G2a, G2bt,
      (long)mt * 128, blockIdx.y * 128, KX, smem, smem + 8192);
}

// spmm_add: C = f(L_b · Bt_b^T + Cadd + bias), batched; batch b on XCD b/2.
template <int NP, int NT, int NR, int NSTO, bool OBF16>
__global__ __launch_bounds__(256) void spmm_add(
    const u16* __restrict__ L, const u16* __restrict__ Bt,
    const float* __restrict__ Cadd, int lda,
    const float* __restrict__ bias, void* __restrict__ C, int ldc)
{
  __shared__ __align__(16) u16 smem[(128 + NT) * 64];
  constexpr int TPB = 4 * (NP / NT);
  const int blk = blockIdx.x;
  const int xcd = blk & 7, sub = blk >> 3;
  const int b = xcd * 2 + sub / TPB;
  const int t = sub % TPB;
  const int mt = t & 3, nt = t >> 2;
  gemm_core<512, NT, 1, 0, NR, NSTO, 0, OBF16>(
      L + ((size_t)b * 512 + mt * 128) * 512,
      Bt + ((size_t)b * NP + nt * NT) * 512,
      bias, Cadd, lda, C, nullptr,
      (long)b * 512 + mt * 128, nt * NT, ldc, smem, smem + 8192);
}

// ---------------------------------------------------------------------------
extern "C" void kernel_launch(void* const* d_in, const int* in_sizes, int n_in,
                              void* d_out, int out_size, void* d_ws, size_t ws_size,
                              hipStream_t stream) {
  const float* x4  = (const float*)d_in[0];
  const float* att = (const float*)d_in[1];
  const float* W1  = (const float*)d_in[2];
  const float* b1  = (const float*)d_in[3];
  const float* W2  = (const float*)d_in[4];
  const float* b2  = (const float*)d_in[5];
  float* out = (float*)d_out;

  char* ws = (char*)d_ws;
  f32x4* Xpad = (f32x4*)ws;                                  // 20.97 MB
  float* G2a  = (float*)ws;                                  // aliases Xpad (dead after g1_bl)
  ws += (size_t)ROWS * F4 * 16;
  u16* Xb    = (u16*)ws;                                     // 10.49 MB
  u16* G2bt  = (u16*)ws;                                     // aliases Xb (dead after g1_bl)
  ws += (size_t)ROWS * KX * 2;
  u16* W1ct = (u16*)ws;  ws += (size_t)1920 * KX * 2;        //  2.46 MB
  u16* W2ct = (u16*)ws;  ws += (size_t)1280 * KH * 2;        //  2.46 MB
  u16* Lm   = (u16*)ws;  ws += (size_t)NB * 512 * 512 * 2;   //  8.39 MB
  float* G1a = (float*)ws; ws += (size_t)ROWS * KH * 4;      // 31.46 MB
  u16* G1bt = (u16*)ws;  ws += (size_t)NB * KH * 512 * 2;    // 15.73 MB
  u16* hB   = (u16*)ws;  ws += (size_t)ROWS * KH * 2;        // 15.73 MB
  float* att_s = (float*)ws; ws += (size_t)NB * NN * 4;
  u16* order_  = (u16*)ws;   ws += (size_t)NB * NN * 2;

  prep<<<dim3(6512), 256, 0, stream>>>(x4, att, W1, W2, Xpad, Xb, W1ct, W2ct,
                                       order_, att_s);
  // build_L ∥ G1 (one launch, interleaved block types)
  g1_bl<<<dim3(3008), 256, 0, stream>>>(Xb, W1ct, G1a, G1bt,
                                        Xpad, order_, att_s, Lm);
  // h = relu(G1a + L·G1b + b1); cols 937..959 stored as 0 (K-pad of G2)
  spmm_add<KH, 96, FH, KH, true><<<dim3(640), 256, 0, stream>>>(
      Lm, G1bt, G1a, KH, b1, (void*)hB, KH);
  g2<<<dim3(64, 10), 256, 0, stream>>>(hB, W2ct, G2a, G2bt);
  // out = relu(G2a + L·G2b + b2)
  spmm_add<KX, 64, FF, FF, false><<<dim3(640), 256, 0, stream>>>(
      Lm, G2bt, G2a, KX, b2, (void*)out, FF);
}

// Round 7
// 272.143 us; speedup vs baseline: 1.0234x; 1.0234x over previous
//
#include <hip/hip_runtime.h>
#include <stdint.h>

typedef uint16_t u16;
typedef uint32_t u32;
typedef __attribute__((ext_vector_type(4))) float f32x4;
typedef __attribute__((ext_vector_type(4))) unsigned short us4;

#define NB   16
#define NN   512
#define FF   625      // H*W (= F)
#define FH   937      // int(625*1.5)
#define ROWS 8192     // NB*NN
#define F4   160      // 640/4 f32x4 slots per padded X row
#define GQ   4        // att-adjacent rows per build_L block
#define KX   640      // padded F   (K of G1 / cols of Xb / N-stride of G2a,G2bt)
#define KH   960      // padded Fh  (K of G2 / cols of h / N-stride of G1a,G1bt)
#define N1   1874     // G1 real N (2*937)
#define N2   1250     // G2 real N (2*625)

using frag_ab = __attribute__((ext_vector_type(8))) short;  // 8 bf16
using frag_cd = __attribute__((ext_vector_type(4))) float;  // 4 fp32

__device__ __forceinline__ u16 f32_bf16(float f) {
  union { float f; uint32_t u; } x; x.f = f;
  uint32_t r = x.u + 0x7fffu + ((x.u >> 16) & 1u);   // RNE
  return (u16)(r >> 16);
}
__device__ __forceinline__ void gload_lds16(const void* g, void* l) {
  __builtin_amdgcn_global_load_lds((__attribute__((address_space(1))) void*)g,
                                   (__attribute__((address_space(3))) void*)l,
                                   16, 0, 0);
}

// ---------------------------------------------------------------------------
// prep (R12-proven): re-associated ChebConv — no Xt. Weight transposes split
// on N (output-col concat [Wa|Wb]), not K.
//  [0,16)        att rank-sort per batch -> order[b][512], att_s[b][512]
//  [16,4112)     pad_x: x4 -> Xpad f32x4 + Xb bf16 [8192][640]; XCD-aligned
//  [4112,5312)   W1 -> W1ct [1920][640] B^T  (row n: col of [W1a|W1b])
//  [5312,6512)   W2 -> W2ct [1280][960] B^T
// ---------------------------------------------------------------------------
__global__ __launch_bounds__(256) void prep(
    const float* __restrict__ x4, const float* __restrict__ att,
    const float* __restrict__ W1, const float* __restrict__ W2,
    f32x4* __restrict__ Xpad, u16* __restrict__ Xb,
    u16* __restrict__ W1ct, u16* __restrict__ W2ct,
    u16* __restrict__ order, float* __restrict__ att_s)
{
  __shared__ __align__(16) float smem[1056];   // unioned: sort 512 / tile 32x33
  const int blk = blockIdx.x;
  const int tid = threadIdx.x;

  if (blk < 16) {
    // att rank-sort: rank = #{j: a_j < a_i || (== && j<i)}
    float* a_sh = smem;
    const int b = blk;
    a_sh[tid]       = att[b * NN + tid];
    a_sh[tid + 256] = att[b * NN + tid + 256];
    __syncthreads();
    #pragma unroll
    for (int h = 0; h < 2; ++h) {
      const int i = tid + h * 256;
      const float ai = a_sh[i];
      int r = 0;
      for (int j = 0; j < NN; ++j) {
        const float aj = a_sh[j];
        r += (aj < ai) || (aj == ai && j < i);
      }
      order[(size_t)b * NN + r] = (u16)i;
      att_s[(size_t)b * NN + r] = ai;
    }
  } else if (blk < 4112) {
    const int idx = blk - 16;
    const int xcd = idx & 7, loc = idx >> 3;    // loc 0..511
    const int row0 = xcd * 1024 + loc * 2;
    for (int s = tid; s < 320; s += 256) {
      const int row = row0 + (s >= 160);
      const int k4 = (s >= 160) ? s - 160 : s;
      f32x4 v; us4 o;
      #pragma unroll
      for (int t = 0; t < 4; ++t) {
        const int f = k4 * 4 + t;
        float x = (f < FF) ? x4[(size_t)row * FF + f] : 0.f;
        v[t] = x; o[t] = f32_bf16(x);
      }
      Xpad[(size_t)row * F4 + k4] = v;
      *(us4*)(Xb + (size_t)row * KX + k4 * 4) = o;
    }
  } else if (blk < 5312) {
    float (*tile)[33] = (float(*)[33])smem;
    const int bb = blk - 4112;                  // 20 kt x 60 nt
    const int kt = bb % 20, ntl = bb / 20;
    const int tx = tid & 31, ty = tid >> 5;
    #pragma unroll
    for (int r = 0; r < 4; ++r) {
      const int k = kt * 32 + ty + r * 8;       // 0..639 (F index)
      const int n = ntl * 32 + tx;              // 0..1919 (col of [W1a|W1b])
      float v = 0.f;
      int c = -1, np = 0;
      if (n < 937) { c = 0; np = n; }
      else if (n < 1874) { c = 1; np = n - 937; }
      if (c >= 0 && k < 625) v = W1[((size_t)c * 625 + k) * FH + np];
      tile[ty + r * 8][tx] = v;
    }
    __syncthreads();
    #pragma unroll
    for (int r = 0; r < 4; ++r) {
      const int n = ntl * 32 + ty + r * 8;
      const int k = kt * 32 + tx;
      W1ct[(size_t)n * KX + k] = f32_bf16(tile[tx][ty + r * 8]);
    }
  } else {
    float (*tile)[33] = (float(*)[33])smem;
    const int bb = blk - 5312;                  // 30 kt x 40 nt
    const int kt = bb % 30, ntl = bb / 30;
    const int tx = tid & 31, ty = tid >> 5;
    #pragma unroll
    for (int r = 0; r < 4; ++r) {
      const int k = kt * 32 + ty + r * 8;       // 0..959 (Fh index)
      const int n = ntl * 32 + tx;              // 0..1279 (col of [W2a|W2b])
      float v = 0.f;
      int c = -1, np = 0;
      if (n < 625) { c = 0; np = n; }
      else if (n < 1250) { c = 1; np = n - 625; }
      if (c >= 0 && k < 937) v = W2[((size_t)c * 937 + k) * FF + np];
      tile[ty + r * 8][tx] = v;
    }
    __syncthreads();
    #pragma unroll
    for (int r = 0; r < 4; ++r) {
      const int n = ntl * 32 + ty + r * 8;
      const int k = kt * 32 + tx;
      W2ct[(size_t)n * KH + k] = f32_bf16(tile[tx][ty + r * 8]);
    }
  }
}

// ---------------------------------------------------------------------------
// build_L (R9-proven, standalone again — R13: unfused from G1 so it gets its
// own resource shape back: 7KB LDS, ~48 VGPR, high occupancy).
// ---------------------------------------------------------------------------
__global__ __launch_bounds__(256) void build_L(
    const f32x4* __restrict__ Xpad,   // [ROWS][160]
    const u16* __restrict__ order,    // [NB][512]
    const float* __restrict__ att_s,  // [NB][512] ascending
    u16* __restrict__ L)              // [NB][512][512] bf16 row-major
{
  __shared__ float atts[512];
  __shared__ u16 ords[512];
  __shared__ u16 cand[512];          // sorted positions in window
  __shared__ u16 flag[GQ][512];
  __shared__ int ncand, naccs[GQ];

  const int tid = threadIdx.x;
  const int blk = blockIdx.x;
  const int xcd = blk & 7, sub = blk >> 3;     // sub 0..255
  const int b = xcd * 2 + (sub >> 7);
  const int p0 = (sub & 127) * GQ;             // sorted-position base
  const f32x4* Xb4 = Xpad + (size_t)b * NN * F4;

  atts[tid]       = att_s[b * NN + tid];
  atts[tid + 256] = att_s[b * NN + tid + 256];
  ords[tid]       = order[b * NN + tid];
  ords[tid + 256] = order[b * NN + tid + 256];
  {
    u32* fz = (u32*)&flag[0][0];               // GQ*512 u16 = 1024 u32
    #pragma unroll
    for (int s = 0; s < GQ; ++s) fz[tid + s * 256] = 0;
  }
  if (tid == 0) ncand = 0;
  if (tid < GQ) naccs[tid] = 0;
  __syncthreads();

  float av[GQ]; int ig[GQ];
  #pragma unroll
  for (int g = 0; g < GQ; ++g) { av[g] = atts[p0 + g]; ig[g] = ords[p0 + g]; }
  if (tid < GQ) flag[tid][ords[p0 + tid]] = 1;   // self (A+I diagonal)

  {
    const float lo = av[0] - 0.0501f, hi = av[GQ - 1] + 0.0501f;
    const bool q0 = (atts[tid] >= lo) && (atts[tid] <= hi);
    const bool q1 = (atts[tid + 256] >= lo) && (atts[tid + 256] <= hi);
    const unsigned long long m0 = __ballot(q0);
    const unsigned long long m1 = __ballot(q1);
    const int c0 = __popcll(m0);
    const int c1 = __popcll(m1);
    const int lane = tid & 63;
    int base = 0;
    if (lane == 0 && (c0 + c1)) base = atomicAdd(&ncand, c0 + c1);
    base = __shfl(base, 0, 64);
    const unsigned long long below = (1ull << lane) - 1ull;
    if (q0) cand[base + __popcll(m0 & below)] = (u16)tid;
    if (q1) cand[base + c0 + __popcll(m1 & below)] = (u16)(tid + 256);
  }
  __syncthreads();
  const int nc = ncand;

  const int hl = tid & 31;          // half-lane
  const int hw = tid >> 5;          // half-wave group 0..7

  f32x4 xi[GQ][5];
  #pragma unroll
  for (int g = 0; g < GQ; ++g) {
    const f32x4* Xi = Xb4 + (size_t)ig[g] * F4;
    #pragma unroll
    for (int s = 0; s < 5; ++s) xi[g][s] = Xi[s * 32 + hl];
  }

  for (int c = hw; c < nc; c += 8) {
    const int p = cand[c];
    const int j = ords[p];
    const float aj = atts[p];
    const f32x4* Xj = Xb4 + (size_t)j * F4;
    f32x4 xj[5];
    #pragma unroll
    for (int s = 0; s < 5; ++s) xj[s] = Xj[s * 32 + hl];

    float pd[GQ];
    #pragma unroll
    for (int g = 0; g < GQ; ++g) {
      float p2 = 0.f;   // EXACT summation order of the original per-row kernel
      #pragma unroll
      for (int t = 0; t < 4; ++t) {
        p2 += fabsf(xi[g][0][t] - xj[0][t]) + fabsf(xi[g][1][t] - xj[1][t])
            + fabsf(xi[g][2][t] - xj[2][t]) + fabsf(xi[g][3][t] - xj[3][t])
            + fabsf(xi[g][4][t] - xj[4][t]);
      }
      pd[g] = p2;
    }
    #pragma unroll
    for (int off = 16; off; off >>= 1) {
      #pragma unroll
      for (int g = 0; g < GQ; ++g) pd[g] += __shfl_xor(pd[g], off, 64);
    }
    if (hl == 0) {
      #pragma unroll
      for (int g = 0; g < GQ; ++g) {
        if (pd[g] <= 180.0f && fabsf(av[g] - aj) <= 0.05f && j != ig[g]) {
          flag[g][j] = 1;
          atomicAdd(&naccs[g], 1);
        }
      }
    }
  }
  __syncthreads();

  #pragma unroll
  for (int g = 0; g < GQ; ++g) {
    const u16 dv = f32_bf16(1.0f / (float)(naccs[g] + 1));
    const long row = (long)b * NN + ig[g];
    const u32 lo2 = flag[g][2 * tid]     ? (u32)dv : 0u;
    const u32 hi2 = flag[g][2 * tid + 1] ? (u32)dv : 0u;
    *(u32*)(L + (size_t)row * 512 + 2 * tid) = lo2 | (hi2 << 16);
  }
}

// ---------------------------------------------------------------------------
// gemm_core (R12-proven). LDS passed in by caller. Two epilogue modes:
//  MODE 0 (G-split): cols < NA -> f32 normal store into C (ldc); cols in
//    [NA,NSTO) -> bf16 TRANSPOSED per batch into Ct[(b*NPB + col-NA)*512+node].
//  MODE 1 (S): v = col<NR ? relu(acc + Cadd[row*lda+col] + bias[col]) : 0,
//    stored for col < NSTO (bf16 or f32).
// ---------------------------------------------------------------------------
template <int KS, int NTILE, int MODE, int NA, int NR, int NSTO, int NPB, bool OBF16>
__device__ __forceinline__ void gemm_core(
    const u16* __restrict__ At,      // A tile base: rows 0..127, stride KS
    const u16* __restrict__ Btt,     // B^T tile base: rows 0..NTILE-1, stride KS
    const float* __restrict__ bias, const float* __restrict__ Cadd, int lda,
    void* __restrict__ C, u16* __restrict__ Ct,
    long crow0, int col0, int ldc,
    u16* Ash, u16* Bsh)
{
  constexpr int NI = NTILE / 32;
  constexpr int BR = NTILE / 32;

  const int tid  = threadIdx.x;
  const int lane = tid & 63;
  const int wave = tid >> 6;
  const int wm = wave & 1, wn = wave >> 1;
  const int q = lane >> 4, l16 = lane & 15;

  const u16* pa[4]; const u16* pb[BR];
  #pragma unroll
  for (int r = 0; r < 4; ++r) {
    const int ci = r * 256 + tid;
    const int row = ci >> 3, cpos = ci & 7;
    pa[r] = At + (size_t)row * KS + (cpos ^ (row & 7)) * 8;
  }
  #pragma unroll
  for (int r = 0; r < BR; ++r) {
    const int ci = r * 256 + tid;
    const int row = ci >> 3, cpos = ci & 7;
    pb[r] = Btt + (size_t)row * KS + (cpos ^ (row & 7)) * 8;
  }
  const int wbase = (tid & 192) * 8;

  const frag_ab* fA[4][2]; const frag_ab* fB[NI][2];
  #pragma unroll
  for (int mi = 0; mi < 4; ++mi) {
    const int row = wm * 64 + mi * 16 + l16;
    fA[mi][0] = (const frag_ab*)&Ash[row * 64 + ((q    ) ^ (l16 & 7)) * 8];
    fA[mi][1] = (const frag_ab*)&Ash[row * 64 + ((q + 4) ^ (l16 & 7)) * 8];
  }
  #pragma unroll
  for (int ni = 0; ni < NI; ++ni) {
    const int row = wn * (NTILE / 2) + ni * 16 + l16;
    fB[ni][0] = (const frag_ab*)&Bsh[row * 64 + ((q    ) ^ (l16 & 7)) * 8];
    fB[ni][1] = (const frag_ab*)&Bsh[row * 64 + ((q + 4) ^ (l16 & 7)) * 8];
  }

  frag_cd acc[4][NI] = {};

  constexpr int KT = KS / 64;
  for (int kt = 0; kt < KT; ++kt) {
    __syncthreads();
    #pragma unroll
    for (int r = 0; r < 4; ++r) { gload_lds16(pa[r], &Ash[r * 2048 + wbase]); pa[r] += 64; }
    #pragma unroll
    for (int r = 0; r < BR; ++r) { gload_lds16(pb[r], &Bsh[r * 2048 + wbase]); pb[r] += 64; }
    __syncthreads();

    #pragma unroll
    for (int kk = 0; kk < 2; ++kk) {
      frag_ab av[4], bv[NI];
      #pragma unroll
      for (int mi = 0; mi < 4; ++mi) av[mi] = *fA[mi][kk];
      #pragma unroll
      for (int ni = 0; ni < NI; ++ni) bv[ni] = *fB[ni][kk];
      #pragma unroll
      for (int mi = 0; mi < 4; ++mi)
        #pragma unroll
        for (int ni = 0; ni < NI; ++ni)
          acc[mi][ni] = __builtin_amdgcn_mfma_f32_16x16x32_bf16(
              av[mi], bv[ni], acc[mi][ni], 0, 0, 0);
    }
  }

  #pragma unroll
  for (int ni = 0; ni < NI; ++ni) {
    const int col = col0 + wn * (NTILE / 2) + ni * 16 + l16;
    if (col >= NSTO) continue;
    if (MODE == 0) {
      const bool wt = (col >= NA);
      #pragma unroll
      for (int mi = 0; mi < 4; ++mi) {
        us4 tv;
        #pragma unroll
        for (int r = 0; r < 4; ++r) {
          const long rowg = crow0 + wm * 64 + mi * 16 + q * 4 + r;
          const float v = acc[mi][ni][r];
          if (wt) tv[r] = f32_bf16(v);
          else    ((float*)C)[rowg * (size_t)ldc + col] = v;
        }
        if (wt) {
          const long bb = crow0 >> 9;
          const int node = (int)(crow0 & 511) + wm * 64 + mi * 16 + q * 4;
          *(us4*)(Ct + ((size_t)bb * NPB + (col - NA)) * 512 + node) = tv;
        }
      }
    } else {
      const bool ok = (col < NR);
      const float bv = ok ? bias[col] : 0.f;
      #pragma unroll
      for (int mi = 0; mi < 4; ++mi) {
        #pragma unroll
        for (int r = 0; r < 4; ++r) {
          const long rowg = crow0 + wm * 64 + mi * 16 + q * 4 + r;
          float v = 0.f;
          if (ok) v = fmaxf(acc[mi][ni][r] + Cadd[rowg * (size_t)lda + col] + bv, 0.f);
          if (OBF16) ((u16*)C)[rowg * (size_t)ldc + col] = f32_bf16(v);
          else       ((float*)C)[rowg * (size_t)ldc + col] = v;
        }
      }
    }
  }
}

// G1 = Xb·[W1a|W1b]: cols<937 -> G1a f32; cols 937..1873 -> G1bt bf16 transposed.
__global__ __launch_bounds__(256) void g1(
    const u16* __restrict__ Xb, const u16* __restrict__ W1ct,
    float* __restrict__ G1a, u16* __restrict__ G1bt)
{
  __shared__ __align__(16) u16 smem[16384];
  const int x = blockIdx.x;
  const int mt = ((x & 7) << 3) | (x >> 3);     // XCD-aligned m-tile
  gemm_core<KX, 128, 0, FH, N1, N1, KH, false>(
      Xb + (size_t)mt * 128 * KX, W1ct + (size_t)blockIdx.y * 128 * KX,
      nullptr, nullptr, 0, (void*)G1a, G1bt,
      (long)mt * 128, blockIdx.y * 128, KH, smem, smem + 8192);
}

// G2 = h·[W2a|W2b]: cols<625 -> G2a f32; cols 625..1249 -> G2bt bf16 transposed.
__global__ __launch_bounds__(256) void g2(
    const u16* __restrict__ h, const u16* __restrict__ W2ct,
    float* __restrict__ G2a, u16* __restrict__ G2bt)
{
  __shared__ __align__(16) u16 smem[16384];
  const int x = blockIdx.x;
  const int mt = ((x & 7) << 3) | (x >> 3);
  gemm_core<KH, 128, 0, FF, N2, N2, KX, false>(
      h + (size_t)mt * 128 * KH, W2ct + (size_t)blockIdx.y * 128 * KH,
      nullptr, nullptr, 0, (void*)G2a, G2bt,
      (long)mt * 128, blockIdx.y * 128, KX, smem, smem + 8192);
}

// spmm_add: C = f(L_b · Bt_b^T + Cadd + bias), batched; batch b on XCD b/2.
template <int NP, int NT, int NR, int NSTO, bool OBF16>
__global__ __launch_bounds__(256) void spmm_add(
    const u16* __restrict__ L, const u16* __restrict__ Bt,
    const float* __restrict__ Cadd, int lda,
    const float* __restrict__ bias, void* __restrict__ C, int ldc)
{
  __shared__ __align__(16) u16 smem[(128 + NT) * 64];
  constexpr int TPB = 4 * (NP / NT);
  const int blk = blockIdx.x;
  const int xcd = blk & 7, sub = blk >> 3;
  const int b = xcd * 2 + sub / TPB;
  const int t = sub % TPB;
  const int mt = t & 3, nt = t >> 2;
  gemm_core<512, NT, 1, 0, NR, NSTO, 0, OBF16>(
      L + ((size_t)b * 512 + mt * 128) * 512,
      Bt + ((size_t)b * NP + nt * NT) * 512,
      bias, Cadd, lda, C, nullptr,
      (long)b * 512 + mt * 128, nt * NT, ldc, smem, smem + 8192);
}

// ---------------------------------------------------------------------------
extern "C" void kernel_launch(void* const* d_in, const int* in_sizes, int n_in,
                              void* d_out, int out_size, void* d_ws, size_t ws_size,
                              hipStream_t stream) {
  const float* x4  = (const float*)d_in[0];
  const float* att = (const float*)d_in[1];
  const float* W1  = (const float*)d_in[2];
  const float* b1  = (const float*)d_in[3];
  const float* W2  = (const float*)d_in[4];
  const float* b2  = (const float*)d_in[5];
  float* out = (float*)d_out;

  char* ws = (char*)d_ws;
  f32x4* Xpad = (f32x4*)ws;                                  // 20.97 MB
  float* G2a  = (float*)ws;                                  // aliases Xpad (dead after build_L)
  ws += (size_t)ROWS * F4 * 16;
  u16* Xb    = (u16*)ws;                                     // 10.49 MB
  u16* G2bt  = (u16*)ws;                                     // aliases Xb (dead after g1)
  ws += (size_t)ROWS * KX * 2;
  u16* W1ct = (u16*)ws;  ws += (size_t)1920 * KX * 2;        //  2.46 MB
  u16* W2ct = (u16*)ws;  ws += (size_t)1280 * KH * 2;        //  2.46 MB
  u16* Lm   = (u16*)ws;  ws += (size_t)NB * 512 * 512 * 2;   //  8.39 MB
  float* G1a = (float*)ws; ws += (size_t)ROWS * KH * 4;      // 31.46 MB
  u16* G1bt = (u16*)ws;  ws += (size_t)NB * KH * 512 * 2;    // 15.73 MB
  u16* hB   = (u16*)ws;  ws += (size_t)ROWS * KH * 2;        // 15.73 MB
  float* att_s = (float*)ws; ws += (size_t)NB * NN * 4;
  u16* order_  = (u16*)ws;   ws += (size_t)NB * NN * 2;

  prep<<<dim3(6512), 256, 0, stream>>>(x4, att, W1, W2, Xpad, Xb, W1ct, W2ct,
                                       order_, att_s);
  build_L<<<dim3(2048), 256, 0, stream>>>(Xpad, order_, att_s, Lm);
  g1<<<dim3(64, 15), 256, 0, stream>>>(Xb, W1ct, G1a, G1bt);
  // h = relu(G1a + L·G1b + b1); cols 937..959 stored as 0 (K-pad of G2)
  spmm_add<KH, 96, FH, KH, true><<<dim3(640), 256, 0, stream>>>(
      Lm, G1bt, G1a, KH, b1, (void*)hB, KH);
  g2<<<dim3(64, 10), 256, 0, stream>>>(hB, W2ct, G2a, G2bt);
  // out = relu(G2a + L·G2b + b2)
  spmm_add<KX, 64, FF, FF, false><<<dim3(640), 256, 0, stream>>>(
      Lm, G2bt, G2a, KX, b2, (void*)out, FF);
}

// Round 8
// 218.445 us; speedup vs baseline: 1.2749x; 1.2458x over previous
//
#include <hip/hip_runtime.h>
#include <stdint.h>

typedef uint16_t u16;
typedef uint32_t u32;
typedef __attribute__((ext_vector_type(4))) float f32x4;
typedef __attribute__((ext_vector_type(4))) unsigned short us4;
typedef __attribute__((ext_vector_type(8))) unsigned short us8;

#define NB   16
#define NN   512
#define FF   625      // H*W
#define FH   937      // int(625*1.5)
#define ROWS 8192     // NB*NN
#define KS1  1280     // [X(625) pad->640 | t1(625) pad->640]
#define KS2  1920     // [h(937) pad->960 | t2(937) pad->960]
#define NPX  640      // padded F   (t1 cols / Xt rows per batch)
#define NPH  960      // padded Fh  (t2 cols / ht rows per batch)
#define F4   160      // 640/4 f32x4 slots per padded X row
#define GQ   4        // att-adjacent rows per build_L block

using frag_ab = __attribute__((ext_vector_type(8))) short;  // 8 bf16
using frag_cd = __attribute__((ext_vector_type(4))) float;  // 4 fp32

__device__ __forceinline__ u16 f32_bf16(float f) {
  union { float f; uint32_t u; } x; x.f = f;
  uint32_t r = x.u + 0x7fffu + ((x.u >> 16) & 1u);   // RNE
  return (u16)(r >> 16);
}
__device__ __forceinline__ void gload_lds16(const void* g, void* l) {
  __builtin_amdgcn_global_load_lds((__attribute__((address_space(1))) void*)g,
                                   (__attribute__((address_space(3))) void*)l,
                                   16, 0, 0);
}

// ---------------------------------------------------------------------------
// prep (R10-proven): single-pass fused, sort first, unioned 8448B LDS.
//  [0,16)        att rank-sort per batch -> order[b][512], att_s[b][512]
//  [16,1040)     fused: x4 -> Xpad + Xcat(lo) + Xt in ONE pass (x4 read once)
//  [1040,2320)   W1 -> W1t [1024][KS1]
//  [2320,3520)   W2 -> W2t [640][KS2]
// ---------------------------------------------------------------------------
__global__ __launch_bounds__(256) void prep(
    const float* __restrict__ x4, const float* __restrict__ att,
    const float* __restrict__ W1, const float* __restrict__ W2,
    f32x4* __restrict__ Xpad, u16* __restrict__ Xcat, u16* __restrict__ Xt,
    u16* __restrict__ W1t, u16* __restrict__ W2t,
    u16* __restrict__ order, float* __restrict__ att_s)
{
  __shared__ __align__(16) float smem[2112];   // 8448 B, unioned across branches
  const int blk = blockIdx.x;
  const int tid = threadIdx.x;

  if (blk < 16) {
    // att rank-sort: one block per batch. rank = #{j: a_j < a_i || (== && j<i)}
    float* a_sh = smem;
    const int b = blk;
    a_sh[tid]       = att[b * NN + tid];
    a_sh[tid + 256] = att[b * NN + tid + 256];
    __syncthreads();
    #pragma unroll
    for (int h = 0; h < 2; ++h) {
      const int i = tid + h * 256;
      const float ai = a_sh[i];
      int r = 0;
      for (int j = 0; j < NN; ++j) {
        const float aj = a_sh[j];
        r += (aj < ai) || (aj == ai && j < i);
      }
      order[(size_t)b * NN + r] = (u16)i;
      att_s[(size_t)b * NN + r] = ai;
    }
  } else if (blk < 1040) {
    // fused pad_x + Xt. T[buf][r][c] = smem[buf*1056 + r*33 + c]
    float* T = smem;
    const int idx = blk - 16;
    const int xcd = idx & 7, sub = idx >> 3;    // sub 0..127
    const int b = xcd * 2 + (sub >> 6);
    const int rr = sub & 63;
    const int q = rr >> 4;                      // f-quarter 0..3
    const int nt = rr & 15;                     // node-tile 0..15
    const int node0 = nt * 32;
    const int tx = tid & 31, ty = tid >> 5;     // load mapping
    const int lrow = tid >> 3, lcol = tid & 7;  // process mapping

    int buf = 0;
    {
      const int f0 = q * 160;
      #pragma unroll
      for (int r = 0; r < 4; ++r) {
        const int node = node0 + ty + r * 8;
        const int f = f0 + tx;
        T[(ty + r * 8) * 33 + tx] = (f < FF) ? x4[((size_t)b * NN + node) * FF + f] : 0.f;
      }
    }
    __syncthreads();

    for (int c = 0; c < 5; ++c) {
      const int f0 = q * 160 + c * 32;
      float vnext[4];
      const bool has = (c + 1 < 5);
      if (has) {
        const int fn = f0 + 32 + tx;
        #pragma unroll
        for (int r = 0; r < 4; ++r) {
          const int node = node0 + ty + r * 8;
          vnext[r] = (fn < FF) ? x4[((size_t)b * NN + node) * FF + fn] : 0.f;
        }
      }
      // (a) Xpad + Xcat: thread = node_l*8 + k4s
      {
        const int node_l = lrow, k4s = lcol;
        const size_t grow = (size_t)b * NN + node0 + node_l;
        const int k4 = q * 40 + c * 8 + k4s;
        f32x4 v; us4 o;
        #pragma unroll
        for (int t = 0; t < 4; ++t) {
          const float x = T[buf * 1056 + node_l * 33 + k4s * 4 + t];
          v[t] = x; o[t] = f32_bf16(x);
        }
        Xpad[grow * F4 + k4] = v;
        *(us4*)(Xcat + grow * KS1 + k4 * 4) = o;
      }
      // (b) Xt: thread = fl*8 + nl, writes 4 nodes (us4) of row f0+fl
      {
        const int fl = lrow, nl = lcol;
        const int f = f0 + fl;
        us4 ov;
        #pragma unroll
        for (int t = 0; t < 4; ++t)
          ov[t] = f32_bf16(T[buf * 1056 + (nl * 4 + t) * 33 + fl]);
        *(us4*)(Xt + ((size_t)b * NPX + f) * 512 + node0 + nl * 4) = ov;
      }
      if (has) {
        #pragma unroll
        for (int r = 0; r < 4; ++r)
          T[(buf ^ 1) * 1056 + (ty + r * 8) * 33 + tx] = vnext[r];
        __syncthreads();
        buf ^= 1;
      }
    }
  } else if (blk < 2320) {
    float (*tile)[33] = (float(*)[33])smem;
    const int bb = blk - 1040;                  // 40 kt x 32 nt
    const int kt = bb % 40, nt = bb / 40;
    const int tx = tid & 31, ty = tid >> 5;
    #pragma unroll
    for (int r = 0; r < 4; ++r) {
      int k = kt * 32 + ty + r * 8;
      int n = nt * 32 + tx;
      float v = 0.f;
      int c = -1, kk = 0;
      if (k < 625) { c = 0; kk = k; }
      else if (k >= 640 && k < 1265) { c = 1; kk = k - 640; }
      if (c >= 0 && n < FH) v = W1[((size_t)c * 625 + kk) * FH + n];
      tile[ty + r * 8][tx] = v;
    }
    __syncthreads();
    #pragma unroll
    for (int r = 0; r < 4; ++r) {
      int n = nt * 32 + ty + r * 8;
      int k = kt * 32 + tx;
      W1t[(size_t)n * KS1 + k] = f32_bf16(tile[tx][ty + r * 8]);
    }
  } else {
    float (*tile)[33] = (float(*)[33])smem;
    const int bb = blk - 2320;                  // 60 kt x 20 nt
    const int kt = bb % 60, nt = bb / 60;
    const int tx = tid & 31, ty = tid >> 5;
    #pragma unroll
    for (int r = 0; r < 4; ++r) {
      int k = kt * 32 + ty + r * 8;
      int n = nt * 32 + tx;
      float v = 0.f;
      int c = -1, kk = 0;
      if (k < 937) { c = 0; kk = k; }
      else if (k >= 960 && k < 1897) { c = 1; kk = k - 960; }
      if (c >= 0 && n < FF) v = W2[((size_t)c * 937 + kk) * FF + n];
      tile[ty + r * 8][tx] = v;
    }
    __syncthreads();
    #pragma unroll
    for (int r = 0; r < 4; ++r) {
      int n = nt * 32 + ty + r * 8;
      int k = kt * 32 + tx;
      W2t[(size_t)n * KS2 + k] = f32_bf16(tile[tx][ty + r * 8]);
    }
  }
}

// ---------------------------------------------------------------------------
// build_L (R9-proven): att-sorted row grouping, GQ=4 rows/block, contiguous
// sorted candidate window + exact per-row recheck. Xj loaded once per 4 rows.
// ---------------------------------------------------------------------------
__global__ __launch_bounds__(256) void build_L(
    const f32x4* __restrict__ Xpad,   // [ROWS][160]
    const u16* __restrict__ order,    // [NB][512]
    const float* __restrict__ att_s,  // [NB][512] ascending
    u16* __restrict__ L)              // [NB][512][512] bf16 row-major
{
  __shared__ float atts[512];
  __shared__ u16 ords[512];
  __shared__ u16 cand[512];
  __shared__ u16 flag[GQ][512];
  __shared__ int ncand, naccs[GQ];

  const int tid = threadIdx.x;
  const int blk = blockIdx.x;
  const int xcd = blk & 7, sub = blk >> 3;     // sub 0..255
  const int b = xcd * 2 + (sub >> 7);
  const int p0 = (sub & 127) * GQ;
  const f32x4* Xb4 = Xpad + (size_t)b * NN * F4;

  atts[tid]       = att_s[b * NN + tid];
  atts[tid + 256] = att_s[b * NN + tid + 256];
  ords[tid]       = order[b * NN + tid];
  ords[tid + 256] = order[b * NN + tid + 256];
  {
    u32* fz = (u32*)&flag[0][0];               // GQ*512 u16 = 1024 u32
    #pragma unroll
    for (int s = 0; s < GQ; ++s) fz[tid + s * 256] = 0;
  }
  if (tid == 0) ncand = 0;
  if (tid < GQ) naccs[tid] = 0;
  __syncthreads();

  float av[GQ]; int ig[GQ];
  #pragma unroll
  for (int g = 0; g < GQ; ++g) { av[g] = atts[p0 + g]; ig[g] = ords[p0 + g]; }
  if (tid < GQ) flag[tid][ords[p0 + tid]] = 1;   // self (A+I diagonal)

  {
    const float lo = av[0] - 0.0501f, hi = av[GQ - 1] + 0.0501f;
    const bool q0 = (atts[tid] >= lo) && (atts[tid] <= hi);
    const bool q1 = (atts[tid + 256] >= lo) && (atts[tid + 256] <= hi);
    const unsigned long long m0 = __ballot(q0);
    const unsigned long long m1 = __ballot(q1);
    const int c0 = __popcll(m0);
    const int c1 = __popcll(m1);
    const int lane = tid & 63;
    int base = 0;
    if (lane == 0 && (c0 + c1)) base = atomicAdd(&ncand, c0 + c1);
    base = __shfl(base, 0, 64);
    const unsigned long long below = (1ull << lane) - 1ull;
    if (q0) cand[base + __popcll(m0 & below)] = (u16)tid;
    if (q1) cand[base + c0 + __popcll(m1 & below)] = (u16)(tid + 256);
  }
  __syncthreads();
  const int nc = ncand;

  const int hl = tid & 31;
  const int hw = tid >> 5;

  f32x4 xi[GQ][5];
  #pragma unroll
  for (int g = 0; g < GQ; ++g) {
    const f32x4* Xi = Xb4 + (size_t)ig[g] * F4;
    #pragma unroll
    for (int s = 0; s < 5; ++s) xi[g][s] = Xi[s * 32 + hl];
  }

  for (int c = hw; c < nc; c += 8) {
    const int p = cand[c];
    const int j = ords[p];
    const float aj = atts[p];
    const f32x4* Xj = Xb4 + (size_t)j * F4;
    f32x4 xj[5];
    #pragma unroll
    for (int s = 0; s < 5; ++s) xj[s] = Xj[s * 32 + hl];

    float pd[GQ];
    #pragma unroll
    for (int g = 0; g < GQ; ++g) {
      float p2 = 0.f;   // EXACT summation order of the original per-row kernel
      #pragma unroll
      for (int t = 0; t < 4; ++t) {
        p2 += fabsf(xi[g][0][t] - xj[0][t]) + fabsf(xi[g][1][t] - xj[1][t])
            + fabsf(xi[g][2][t] - xj[2][t]) + fabsf(xi[g][3][t] - xj[3][t])
            + fabsf(xi[g][4][t] - xj[4][t]);
      }
      pd[g] = p2;
    }
    #pragma unroll
    for (int off = 16; off; off >>= 1) {
      #pragma unroll
      for (int g = 0; g < GQ; ++g) pd[g] += __shfl_xor(pd[g], off, 64);
    }
    if (hl == 0) {
      #pragma unroll
      for (int g = 0; g < GQ; ++g) {
        if (pd[g] <= 180.0f && fabsf(av[g] - aj) <= 0.05f && j != ig[g]) {
          flag[g][j] = 1;
          atomicAdd(&naccs[g], 1);
        }
      }
    }
  }
  __syncthreads();

  #pragma unroll
  for (int g = 0; g < GQ; ++g) {
    const u16 dv = f32_bf16(1.0f / (float)(naccs[g] + 1));
    const long row = (long)b * NN + ig[g];
    const u32 lo2 = flag[g][2 * tid]     ? (u32)dv : 0u;
    const u32 hi2 = flag[g][2 * tid + 1] ? (u32)dv : 0u;
    *(u32*)(L + (size_t)row * 512 + 2 * tid) = lo2 | (hi2 << 16);
  }
}

// ---------------------------------------------------------------------------
// gemm_core: 128M x NTILE-N tile, BK=64, XOR chunk swizzle (R5/R6 proven).
// Epilogue: store cols < NSTORE; value = col<NREAL ? f(acc) : 0.
// WT (R11-proven): also store bf16 value TRANSPOSED per batch into
// Ct[(b*NPH+col)*512+node] — replaces the standalone transpose_h kernel;
// per (wave,col) the q/mi/r accumulators form contiguous 8B node-runs.
// ---------------------------------------------------------------------------
template <int KS, int NTILE, int NREAL, int NSTORE, bool RELU, bool BIAS,
          bool OUT_BF16, bool WT>
__device__ __forceinline__ void gemm_core(
    const u16* __restrict__ At,      // A tile base: rows 0..127, stride KS
    const u16* __restrict__ Btt,     // B^T tile base: rows 0..NTILE-1, stride KS
    const float* __restrict__ bias, void* __restrict__ C,
    u16* __restrict__ Ct,            // transposed out (WT only)
    long crow0, int col0, int ldc)
{
  constexpr int NI = NTILE / 32;
  constexpr int BR = NTILE / 32;
  __shared__ __align__(16) u16 Ash[128 * 64];
  __shared__ __align__(16) u16 Bsh[NTILE * 64];

  const int tid  = threadIdx.x;
  const int lane = tid & 63;
  const int wave = tid >> 6;
  const int wm = wave & 1, wn = wave >> 1;
  const int q = lane >> 4, l16 = lane & 15;

  const u16* pa[4]; const u16* pb[BR];
  #pragma unroll
  for (int r = 0; r < 4; ++r) {
    const int ci = r * 256 + tid;
    const int row = ci >> 3, cpos = ci & 7;
    pa[r] = At + (size_t)row * KS + (cpos ^ (row & 7)) * 8;
  }
  #pragma unroll
  for (int r = 0; r < BR; ++r) {
    const int ci = r * 256 + tid;
    const int row = ci >> 3, cpos = ci & 7;
    pb[r] = Btt + (size_t)row * KS + (cpos ^ (row & 7)) * 8;
  }
  const int wbase = (tid & 192) * 8;

  const frag_ab* fA[4][2]; const frag_ab* fB[NI][2];
  #pragma unroll
  for (int mi = 0; mi < 4; ++mi) {
    const int row = wm * 64 + mi * 16 + l16;
    fA[mi][0] = (const frag_ab*)&Ash[row * 64 + ((q    ) ^ (l16 & 7)) * 8];
    fA[mi][1] = (const frag_ab*)&Ash[row * 64 + ((q + 4) ^ (l16 & 7)) * 8];
  }
  #pragma unroll
  for (int ni = 0; ni < NI; ++ni) {
    const int row = wn * (NTILE / 2) + ni * 16 + l16;
    fB[ni][0] = (const frag_ab*)&Bsh[row * 64 + ((q    ) ^ (l16 & 7)) * 8];
    fB[ni][1] = (const frag_ab*)&Bsh[row * 64 + ((q + 4) ^ (l16 & 7)) * 8];
  }

  frag_cd acc[4][NI] = {};

  constexpr int KT = KS / 64;
  for (int kt = 0; kt < KT; ++kt) {
    __syncthreads();
    #pragma unroll
    for (int r = 0; r < 4; ++r) { gload_lds16(pa[r], &Ash[r * 2048 + wbase]); pa[r] += 64; }
    #pragma unroll
    for (int r = 0; r < BR; ++r) { gload_lds16(pb[r], &Bsh[r * 2048 + wbase]); pb[r] += 64; }
    __syncthreads();

    #pragma unroll
    for (int kk = 0; kk < 2; ++kk) {
      frag_ab av[4], bv[NI];
      #pragma unroll
      for (int mi = 0; mi < 4; ++mi) av[mi] = *fA[mi][kk];
      #pragma unroll
      for (int ni = 0; ni < NI; ++ni) bv[ni] = *fB[ni][kk];
      #pragma unroll
      for (int mi = 0; mi < 4; ++mi)
        #pragma unroll
        for (int ni = 0; ni < NI; ++ni)
          acc[mi][ni] = __builtin_amdgcn_mfma_f32_16x16x32_bf16(
              av[mi], bv[ni], acc[mi][ni], 0, 0, 0);
    }
  }

  #pragma unroll
  for (int ni = 0; ni < NI; ++ni) {
    const int col = col0 + wn * (NTILE / 2) + ni * 16 + l16;
    if (col >= NSTORE) continue;
    const bool ok = (col < NREAL);
    float bvv = 0.f;
    if (BIAS) bvv = ok ? bias[col] : 0.f;
    #pragma unroll
    for (int mi = 0; mi < 4; ++mi) {
      us4 tv;
      #pragma unroll
      for (int r = 0; r < 4; ++r) {
        const long rowg = crow0 + wm * 64 + mi * 16 + q * 4 + r;
        float v = acc[mi][ni][r];
        if (BIAS) v += bvv;
        if (RELU) v = fmaxf(v, 0.f);
        if (!ok) v = 0.f;
        if (OUT_BF16) {
          const u16 v16 = f32_bf16(v);
          ((u16*)C)[rowg * (size_t)ldc + col] = v16;
          if (WT) tv[r] = v16;
        } else {
          ((float*)C)[rowg * (size_t)ldc + col] = v;
        }
      }
      if (WT) {
        const long bb = crow0 >> 9;
        const int node = (int)(crow0 & 511) + wm * 64 + mi * 16 + q * 4;
        *(us4*)(Ct + ((size_t)bb * NPH + col) * 512 + node) = tv;
      }
    }
  }
}

// dense: grid (64, Nt); XCD-aligned m-tile (R6)
template <int KS, int NTILE, int NREAL, int NSTORE, bool RELU, bool BIAS,
          bool OUT_BF16, bool WT>
__global__ __launch_bounds__(256) void gemm_dense(
    const u16* __restrict__ A, const u16* __restrict__ Bt,
    const float* __restrict__ bias, void* __restrict__ C,
    u16* __restrict__ Ct, int ldc)
{
  const int x = blockIdx.x;
  const int mt = ((x & 7) << 3) | (x >> 3);
  gemm_core<KS, NTILE, NREAL, NSTORE, RELU, BIAS, OUT_BF16, WT>(
      A + (size_t)mt * 128 * KS, Bt + (size_t)blockIdx.y * NTILE * KS,
      bias, C, Ct, (long)mt * 128, blockIdx.y * NTILE, ldc);
}

// batched spmm: t = L_b · B_b^T; batch b on XCD b/2 (L2-local L/Bt/C).
template <int NP>
__global__ __launch_bounds__(256) void spmm(
    const u16* __restrict__ L, const u16* __restrict__ Bt,
    u16* __restrict__ C, int ldc)
{
  constexpr int TPB = 4 * (NP / 64);
  const int blk = blockIdx.x;
  const int xcd = blk & 7, sub = blk >> 3;
  const int b = xcd * 2 + sub / TPB;
  const int t = sub % TPB;
  const int mt = t & 3, nt = t >> 2;
  gemm_core<512, 64, NP, NP, false, false, true, false>(
      L + ((size_t)b * 512 + mt * 128) * 512,
      Bt + ((size_t)b * NP + nt * 64) * 512,
      nullptr, C, nullptr, (long)b * 512 + mt * 128, nt * 64, ldc);
}

// ---------------------------------------------------------------------------
extern "C" void kernel_launch(void* const* d_in, const int* in_sizes, int n_in,
                              void* d_out, int out_size, void* d_ws, size_t ws_size,
                              hipStream_t stream) {
  const float* x4  = (const float*)d_in[0];
  const float* att = (const float*)d_in[1];
  const float* W1  = (const float*)d_in[2];
  const float* b1  = (const float*)d_in[3];
  const float* W2  = (const float*)d_in[4];
  const float* b2  = (const float*)d_in[5];
  float* out = (float*)d_out;

  char* ws = (char*)d_ws;
  f32x4* Xpad = (f32x4*)ws;                                 // 20.97 MB
  u16* ht = (u16*)ws;       ws += (size_t)ROWS * F4 * 16;   // ht (15.7 MB) aliases
                                                            // Xpad: dead after build_L
  u16* Xcat = (u16*)ws;  ws += (size_t)ROWS * KS1 * 2;      // 20.97 MB
  u16* hcat = (u16*)ws;  ws += (size_t)ROWS * KS2 * 2;      // 31.46 MB
  u16* W1t  = (u16*)ws;  ws += (size_t)1024 * KS1 * 2;      //  2.62 MB
  u16* W2t  = (u16*)ws;  ws += (size_t)640 * KS2 * 2;       //  2.46 MB
  u16* Lm   = (u16*)ws;  ws += (size_t)NB * 512 * 512 * 2;  //  8.39 MB
  u16* Xt   = (u16*)ws;  ws += (size_t)NB * NPX * 512 * 2;  // 10.49 MB
  float* att_s = (float*)ws; ws += (size_t)NB * NN * 4;     // 32 KB
  u16* order_  = (u16*)ws;   ws += (size_t)NB * NN * 2;     // 16 KB

  prep<<<dim3(3520), 256, 0, stream>>>(x4, att, W1, W2, Xpad, Xcat, Xt,
                                       W1t, W2t, order_, att_s);
  build_L<<<dim3(2048), 256, 0, stream>>>(Xpad, order_, att_s, Lm);
  spmm<NPX><<<dim3(640), 256, 0, stream>>>(Lm, Xt, Xcat + NPX, KS1);
  // gemm1 also emits ht (= h^T per batch) directly: transpose_h eliminated.
  gemm_dense<KS1, 128, FH, NPH, true, true, true, true><<<dim3(64, 8), 256, 0, stream>>>(
      Xcat, W1t, b1, (void*)hcat, ht, KS2);
  spmm<NPH><<<dim3(960), 256, 0, stream>>>(Lm, ht, hcat + NPH, KS2);
  gemm_dense<KS2, 64, FF, FF, true, true, false, false><<<dim3(64, 10), 256, 0, stream>>>(
      hcat, W2t, b2, (void*)out, nullptr, FF);
}